// Round 9
// baseline (819.719 us; speedup 1.0000x reference)
//
#include <hip/hip_runtime.h>
#include <cstdint>

#define N_PTS 65536
#define DIM   1024
#define K_CL  256
#define BN    64
#define BK    32
#define NT    (DIM / BK)   // 32 k-tiles
#define THREADS 256

typedef __bf16 bf16_t;
typedef bf16_t bf16x8 __attribute__((ext_vector_type(8)));
typedef float  f32x4  __attribute__((ext_vector_type(4)));

union U16x8 { uint4 u4; bf16x8 bf; ushort us[8]; };

__device__ __forceinline__ ushort f2bf_rne(float f) {
    uint32_t u = __float_as_uint(f);
    uint32_t r = (u + 0x7FFFu + ((u >> 16) & 1u)) >> 16;
    return (ushort)r;
}
__device__ __forceinline__ float bf2f(ushort b) {
    return __uint_as_float(((uint32_t)b) << 16);
}

#define BAR()   __builtin_amdgcn_s_barrier()
#define LGKM0() do { asm volatile("s_waitcnt lgkmcnt(0)" ::: "memory"); \
                     __builtin_amdgcn_sched_barrier(0); } while (0)
#define MFMA(ACC, A, B) (ACC) = __builtin_amdgcn_mfma_f32_16x16x32_bf16((A).bf, (B).bf, (ACC), 0, 0, 0)

// ---------------------------------------------------------------------------
// Kernel 0: centroids fp32 -> PLAIN bf16 hi/lo tile images + c_sq.
// Layout per split: [NT tiles][256 rows][4 groups][8 bf16]  (NO swizzle —
// A is now read per-lane from global, where only coalescing matters: a
// wave's 64 lanes cover 16 rows x 64 B = 1024 contiguous bytes per frag.)
// ---------------------------------------------------------------------------
__global__ __launch_bounds__(128) void km_prep(const float* __restrict__ cent,
                                               ushort* __restrict__ Ahi,
                                               ushort* __restrict__ Alo,
                                               float* __restrict__ csq) {
    const int r  = blockIdx.x;        // centroid row 0..255
    const int j  = threadIdx.x;       // 0..127
    const int kt = j >> 2;
    const int gp = j & 3;
    const int d0 = kt * BK + (gp << 3);

    const float* src = cent + r * DIM + d0;
    float4 a = *(const float4*)src;
    float4 b = *(const float4*)(src + 4);
    float v[8] = {a.x, a.y, a.z, a.w, b.x, b.y, b.z, b.w};

    U16x8 hi, lo;
    float ss = 0.f;
#pragma unroll
    for (int i = 0; i < 8; ++i) {
        float f = v[i];
        ss += f * f;
        ushort h = f2bf_rne(f);
        hi.us[i] = h;
        lo.us[i] = f2bf_rne(f - bf2f(h));
    }
    *(uint4*)(Ahi + kt * (K_CL * BK) + r * BK + gp * 8) = hi.u4;
    *(uint4*)(Alo + kt * (K_CL * BK) + r * BK + gp * 8) = lo.u4;

#pragma unroll
    for (int off = 1; off < 64; off <<= 1) ss += __shfl_xor(ss, off);
    __shared__ float ws2[2];
    if ((j & 63) == 0) ws2[j >> 6] = ss;
    __syncthreads();
    if (j == 0) csq[r] = ws2[0] + ws2[1];
}

// ---------------------------------------------------------------------------
// Kernel 1: fused distances + argmin + loss partial.
// Block = 256 thr (4 waves), tile 256 (all K) x 64 cols; wave = 64 x 64.
// A: NO LDS — each wave reads its own row-fragments straight from global
//    (L2-resident 1 MB, prefetched one K-step ahead into a 2-bank register
//    ring; rows are wave-partitioned so LDS gave zero sharing).
// B: LDS double-buffer (shared by all 4 waves), XOR-swizzled.
// LDS ~19 KB -> 4 co-resident blocks/CU = 16 waves/CU in 4 INDEPENDENT
// barrier domains; ONE barrier per K-step.  Split-bf16: hh + hl + lh.
// ---------------------------------------------------------------------------
__global__ __launch_bounds__(THREADS, 4) void km_main(
    const float* __restrict__ x,
    const ushort* __restrict__ Ahi, const ushort* __restrict__ Alo,
    const float* __restrict__ csq,
    float* __restrict__ out_dist, float* __restrict__ out_assign,
    float* __restrict__ partials) {

    __shared__ __align__(16) ushort sBhi[2][BN * BK];     // 8 KB
    __shared__ __align__(16) ushort sBlo[2][BN * BK];     // 8 KB
    __shared__ __align__(16) float  sCsq[K_CL];           // 1 KB
    __shared__ __align__(16) float  sXsq[BN];
    __shared__ float sRedV[4 * BN];
    __shared__ int   sRedI[4 * BN];
    __shared__ float sWsum[4];

    const int tid  = threadIdx.x;
    const int blk  = blockIdx.x;
    const int lane = tid & 63;
    const int w    = tid >> 6;    // wave owns rows w*64..w*64+63, all 64 cols
    const int l15  = lane & 15;
    const int l4   = lane >> 4;   // 0..3

    sCsq[tid] = csq[tid];

    // B staging: 4 threads per column, 8 d-elements each.
    const int bcol = tid >> 2;                  // 0..63
    const int bq   = tid & 3;                   // d-group
    const int bs   = (bcol >> 1) & 3;           // swizzle key
    const int bOffW = bcol * BK + ((bq ^ bs) << 3);
    const float* xsrc = x + (size_t)(blk * BN + bcol) * DIM + bq * 8;

    float xs_acc = 0.f;

    auto writeB = [&](int buf, float4 u, float4 v) {
        float f[8] = {u.x, u.y, u.z, u.w, v.x, v.y, v.z, v.w};
        U16x8 h, l;
#pragma unroll
        for (int i = 0; i < 8; ++i) {
            float a = f[i];
            xs_acc = fmaf(a, a, xs_acc);
            bf16_t hb = (bf16_t)a;
            h.bf[i] = hb;
            l.bf[i] = (bf16_t)(a - (float)hb);
        }
        *(uint4*)&sBhi[buf][bOffW] = h.u4;
        *(uint4*)&sBlo[buf][bOffW] = l.u4;
    };

    // A fragment global base (ushort units): row = w*64 + l15 (+f*16), grp l4
    const size_t aBase = (size_t)(w * 64 + l15) * BK + l4 * 8;
    const ushort* aHiP = Ahi + aBase;
    const ushort* aLoP = Alo + aBase;
    // frag f at +f*16*BK = +512; tile kt at +kt*8192

    // B fragment LDS offsets (ushort units), swizzle folded in
    int bOff[4];
#pragma unroll
    for (int f = 0; f < 4; ++f) {
        int col = f * 16 + l15;
        bOff[f] = col * BK + ((l4 ^ ((col >> 1) & 3)) << 3);
    }

    // prologue: A(0) frags -> bank0; B(0) convert+write; x(1) prefetch
    U16x8 ah[2][4], al[2][4];
#pragma unroll
    for (int f = 0; f < 4; ++f) {
        ah[0][f].u4 = *(const uint4*)(aHiP + f * 512);
        al[0][f].u4 = *(const uint4*)(aLoP + f * 512);
    }
    float4 p0 = *(const float4*)(xsrc);
    float4 p1 = *(const float4*)(xsrc + 4);
    writeB(0, p0, p1);
    p0 = *(const float4*)(xsrc + BK);
    p1 = *(const float4*)(xsrc + BK + 4);
    __syncthreads();

    f32x4 acc[4][4];
#pragma unroll
    for (int i = 0; i < 4; ++i)
#pragma unroll
        for (int q = 0; q < 4; ++q) acc[i][q] = (f32x4){0.f, 0.f, 0.f, 0.f};

#pragma unroll 2
    for (int kt = 0; kt < NT; ++kt) {
        const int  cur = kt & 1, nxt = cur ^ 1;   // literal under unroll 2
        const bool pf1 = (kt + 1 < NT);
        const bool pf2 = (kt + 2 < NT);

        // B fragments for this K-step (8 ds_read_b128)
        U16x8 bh[4], bl[4];
#pragma unroll
        for (int f = 0; f < 4; ++f) {
            bh[f].u4 = *(const uint4*)&sBhi[cur][bOff[f]];
            bl[f].u4 = *(const uint4*)&sBlo[cur][bOff[f]];
        }

        // A(kt+1) frags -> bank nxt (8 global loads, L2-resident; in flight
        // across the whole MFMA block and the barrier)
        if (pf1) {
            const ushort* ph = aHiP + (size_t)(kt + 1) * 8192;
            const ushort* pl = aLoP + (size_t)(kt + 1) * 8192;
#pragma unroll
            for (int f = 0; f < 4; ++f) {
                ah[nxt][f].u4 = *(const uint4*)(ph + f * 512);
                al[nxt][f].u4 = *(const uint4*)(pl + f * 512);
            }
        }

        // 48 MFMA (A bank cur is register-resident; lgkm for b auto-inserted)
        __builtin_amdgcn_s_setprio(1);
#pragma unroll
        for (int fj = 0; fj < 4; ++fj) {
#pragma unroll
            for (int fi = 0; fi < 4; ++fi) MFMA(acc[fi][fj], ah[cur][fi], bh[fj]);  // hh
#pragma unroll
            for (int fi = 0; fi < 4; ++fi) MFMA(acc[fi][fj], ah[cur][fi], bl[fj]);  // hl
#pragma unroll
            for (int fi = 0; fi < 4; ++fi) MFMA(acc[fi][fj], al[cur][fi], bh[fj]);  // lh
        }
        __builtin_amdgcn_s_setprio(0);

        // convert+write B(kt+1) (compiler's auto-vmcnt proves x(kt+1) regs,
        // leaving the A(kt+1) loads in flight), then load x(kt+2)
        if (pf1) writeB(nxt, p0, p1);
        if (pf2) {
            const float* p = xsrc + (kt + 2) * BK;
            p0 = *(const float4*)p;
            p1 = *(const float4*)(p + 4);
        }
        LGKM0();                    // own b-frag reads + B ds_writes complete
        BAR();                      // sB[nxt] visible block-wide
    }

    // x_sq: 4 threads per column
    {
        float v = xs_acc;
        v += __shfl_xor(v, 1);
        v += __shfl_xor(v, 2);
        if (bq == 0) sXsq[bcol] = v;
    }
    __syncthreads();

    // epilogue: distances, argmin, loss
    float xs[4];
    f32x4 cs[4];
#pragma unroll
    for (int f = 0; f < 4; ++f) {
        xs[f] = sXsq[f * 16 + l15];
        cs[f] = *(const f32x4*)&sCsq[w * 64 + f * 16 + l4 * 4];
    }

    float lsum = 0.f;
    float bestv[4];
    int   bestr[4];
#pragma unroll
    for (int f = 0; f < 4; ++f) { bestv[f] = 3.4e38f; bestr[f] = 0; }

#pragma unroll
    for (int fi = 0; fi < 4; ++fi) {
        const int rowB = w * 64 + fi * 16 + l4 * 4;
#pragma unroll
        for (int fj = 0; fj < 4; ++fj) {
            const int col = blk * BN + fj * 16 + l15;
            float* outp = out_dist + (size_t)rowB * N_PTS + col;
#pragma unroll
            for (int j = 0; j < 4; ++j) {
                float d = cs[fi][j] + xs[fj] - 2.0f * acc[fi][fj][j];
                outp[(size_t)j * N_PTS] = d;
                lsum += d;
                int r = rowB + j;
                if (d < bestv[fj]) { bestv[fj] = d; bestr[fj] = r; }
            }
        }
    }

    // wave argmin over the wave's 64 rows (lanes l, l^16, l^32 share a column)
#pragma unroll
    for (int fj = 0; fj < 4; ++fj) {
#pragma unroll
        for (int m = 16; m <= 32; m <<= 1) {
            float ov = __shfl_xor(bestv[fj], m);
            int   orr = __shfl_xor(bestr[fj], m);
            if (ov < bestv[fj] || (ov == bestv[fj] && orr < bestr[fj])) {
                bestv[fj] = ov; bestr[fj] = orr;
            }
        }
        if (lane < 16) {
            sRedV[w * BN + fj * 16 + lane] = bestv[fj];
            sRedI[w * BN + fj * 16 + lane] = bestr[fj];
        }
    }

#pragma unroll
    for (int off = 1; off < 64; off <<= 1) lsum += __shfl_xor(lsum, off);
    if (lane == 0) sWsum[w] = lsum;
    __syncthreads();

    if (tid < BN) {
        float bv = sRedV[tid];
        int   br = sRedI[tid];
#pragma unroll
        for (int q = 1; q < 4; ++q) {
            float v = sRedV[q * BN + tid];
            int   r = sRedI[q * BN + tid];
            if (v < bv || (v == bv && r < br)) { bv = v; br = r; }
        }
        out_assign[blk * BN + tid] = (float)br;
    }
    if (tid == 0) {
        float t = 0.f;
#pragma unroll
        for (int q = 0; q < 4; ++q) t += sWsum[q];
        partials[blk] = t;
    }
}

// ---------------------------------------------------------------------------
// Kernel 2: deterministic loss reduction over 1024 block partials.
// ---------------------------------------------------------------------------
__global__ __launch_bounds__(1024) void km_fin(const float* __restrict__ partials,
                                               float* __restrict__ out_loss) {
    __shared__ float ws[16];
    const int t = threadIdx.x;
    float v = partials[t];
#pragma unroll
    for (int off = 1; off < 64; off <<= 1) v += __shfl_xor(v, off);
    if ((t & 63) == 0) ws[t >> 6] = v;
    __syncthreads();
    if (t == 0) {
        float s = 0.f;
#pragma unroll
        for (int i = 0; i < 16; ++i) s += ws[i];
        out_loss[0] = s / 16777216.0f;   // mean over K*N
    }
}

extern "C" void kernel_launch(void* const* d_in, const int* in_sizes, int n_in,
                              void* d_out, int out_size, void* d_ws, size_t ws_size,
                              hipStream_t stream) {
    const float* x    = (const float*)d_in[0];
    const float* cent = (const float*)d_in[1];

    float* out        = (float*)d_out;
    float* out_dist   = out;                                  // [256][65536]
    float* out_assign = out + (size_t)K_CL * N_PTS;           // [65536] as float
    float* out_loss   = out_assign + N_PTS;                   // [1]

    char*   ws       = (char*)d_ws;
    float*  csq      = (float*)ws;                            // 256 f32
    float*  partials = (float*)(ws + 1024);                   // 1024 f32
    ushort* Ahi      = (ushort*)(ws + 8192);                  // 512 KB
    ushort* Alo      = (ushort*)(ws + 8192 + 524288);         // 512 KB

    km_prep<<<dim3(K_CL), dim3(128), 0, stream>>>(cent, Ahi, Alo, csq);
    km_main<<<dim3(N_PTS / BN), dim3(THREADS), 0, stream>>>(
        x, Ahi, Alo, csq, out_dist, out_assign, partials);
    km_fin<<<dim3(1), dim3(1024), 0, stream>>>(partials, out_loss);
}

// Round 10
// 137.962 us; speedup vs baseline: 5.9416x; 5.9416x over previous
//
#include <hip/hip_runtime.h>
#include <cstdint>

#define N_PTS 65536
#define DIM   1024
#define K_CL  256
#define BN    64
#define BK    32
#define NT    (DIM / BK)   // 32 k-tiles
#define THREADS 256

typedef __bf16 bf16_t;
typedef bf16_t bf16x8 __attribute__((ext_vector_type(8)));
typedef float  f32x4  __attribute__((ext_vector_type(4)));

union U16x8 { uint4 u4; bf16x8 bf; ushort us[8]; };

__device__ __forceinline__ ushort f2bf_rne(float f) {
    uint32_t u = __float_as_uint(f);
    uint32_t r = (u + 0x7FFFu + ((u >> 16) & 1u)) >> 16;
    return (ushort)r;
}
__device__ __forceinline__ float bf2f(ushort b) {
    return __uint_as_float(((uint32_t)b) << 16);
}

#define BAR()   __builtin_amdgcn_s_barrier()
#define SCHB()  __builtin_amdgcn_sched_barrier(0)
#define LGKM0() do { asm volatile("s_waitcnt lgkmcnt(0)" ::: "memory"); \
                     __builtin_amdgcn_sched_barrier(0); } while (0)
#define MFMA(ACC, A, B) (ACC) = __builtin_amdgcn_mfma_f32_16x16x32_bf16((A).bf, (B).bf, (ACC), 0, 0, 0)

// ---------------------------------------------------------------------------
// Kernel 0: centroids fp32 -> PLAIN bf16 hi/lo tile images + c_sq.
// Layout per split: [NT tiles][256 rows][4 groups][8 bf16]  (no swizzle —
// A is read per-lane from global; a wave's 64 lanes cover 16 rows x 4 groups
// = 1024 contiguous bytes per fragment-quad -> perfectly coalesced.)
// ---------------------------------------------------------------------------
__global__ __launch_bounds__(128) void km_prep(const float* __restrict__ cent,
                                               ushort* __restrict__ Ahi,
                                               ushort* __restrict__ Alo,
                                               float* __restrict__ csq) {
    const int r  = blockIdx.x;        // centroid row 0..255
    const int j  = threadIdx.x;       // 0..127
    const int kt = j >> 2;
    const int gp = j & 3;
    const int d0 = kt * BK + (gp << 3);

    const float* src = cent + r * DIM + d0;
    float4 a = *(const float4*)src;
    float4 b = *(const float4*)(src + 4);
    float v[8] = {a.x, a.y, a.z, a.w, b.x, b.y, b.z, b.w};

    U16x8 hi, lo;
    float ss = 0.f;
#pragma unroll
    for (int i = 0; i < 8; ++i) {
        float f = v[i];
        ss += f * f;
        ushort h = f2bf_rne(f);
        hi.us[i] = h;
        lo.us[i] = f2bf_rne(f - bf2f(h));
    }
    *(uint4*)(Ahi + kt * (K_CL * BK) + r * BK + gp * 8) = hi.u4;
    *(uint4*)(Alo + kt * (K_CL * BK) + r * BK + gp * 8) = lo.u4;

#pragma unroll
    for (int off = 1; off < 64; off <<= 1) ss += __shfl_xor(ss, off);
    __shared__ float ws2[2];
    if ((j & 63) == 0) ws2[j >> 6] = ss;
    __syncthreads();
    if (j == 0) csq[r] = ws2[0] + ws2[1];
}

// ---------------------------------------------------------------------------
// Kernel 1: fused distances + argmin + loss partial.
// Block = 256 thr (4 waves), tile 256 (all K) x 64 cols; wave = 64 x 64.
// A: NO LDS — wave-private row fragments read straight from global (L2-hot
//    1 MB), prefetched one K-step ahead into a 2-bank register ring.
// B: LDS double-buffer (the only shared data), XOR-swizzled.
// LDS ~20 KB; __launch_bounds__(256,2) caps VGPR at 256 (NO spill — r9's
// failure was launch_bounds(,4) forcing acc+ring into scratch).
// -> 2 blocks/CU = 8 waves in 2 INDEPENDENT barrier domains, half the
// per-CU LDS traffic of r6.  One barrier per K-step.
// Split-bf16: hh + hl + lh (numerics identical to r1-r9; absmax 16.0).
// ---------------------------------------------------------------------------
__global__ __launch_bounds__(THREADS, 2) void km_main(
    const float* __restrict__ x,
    const ushort* __restrict__ Ahi, const ushort* __restrict__ Alo,
    const float* __restrict__ csq,
    float* __restrict__ out_dist, float* __restrict__ out_assign,
    float* __restrict__ partials) {

    __shared__ __align__(16) ushort sBhi[2][BN * BK];     // 8 KB
    __shared__ __align__(16) ushort sBlo[2][BN * BK];     // 8 KB
    __shared__ __align__(16) float  sCsq[K_CL];           // 1 KB
    __shared__ __align__(16) float  sXsq[BN];
    __shared__ float sRedV[4 * BN];
    __shared__ int   sRedI[4 * BN];
    __shared__ float sWsum[4];

    const int tid  = threadIdx.x;
    const int blk  = blockIdx.x;
    const int lane = tid & 63;
    const int w    = tid >> 6;    // wave owns rows w*64..w*64+63, all 64 cols
    const int l15  = lane & 15;
    const int l4   = lane >> 4;   // 0..3

    sCsq[tid] = csq[tid];

    // B staging: 4 threads per column, 8 d-elements each.
    const int bcol = tid >> 2;                  // 0..63
    const int bq   = tid & 3;                   // d-group
    const int bs   = (bcol >> 1) & 3;           // swizzle key
    const int bOffW = bcol * BK + ((bq ^ bs) << 3);
    const float* xsrc = x + (size_t)(blk * BN + bcol) * DIM + bq * 8;

    float xs_acc = 0.f;

    auto writeB = [&](int buf, float4 u, float4 v) {
        float f[8] = {u.x, u.y, u.z, u.w, v.x, v.y, v.z, v.w};
        U16x8 h, l;
#pragma unroll
        for (int i = 0; i < 8; ++i) {
            float a = f[i];
            xs_acc = fmaf(a, a, xs_acc);
            bf16_t hb = (bf16_t)a;
            h.bf[i] = hb;
            l.bf[i] = (bf16_t)(a - (float)hb);
        }
        *(uint4*)&sBhi[buf][bOffW] = h.u4;
        *(uint4*)&sBlo[buf][bOffW] = l.u4;
    };

    // A fragment global base (ushort units): row = w*64 + l15 (+f*16), grp l4
    const size_t aBase = (size_t)(w * 64 + l15) * BK + l4 * 8;
    const ushort* aHiP = Ahi + aBase;
    const ushort* aLoP = Alo + aBase;
    // frag f at +f*512 ushorts; tile kt at +kt*8192 ushorts

    // B fragment LDS offsets (ushort units), swizzle folded in
    int bOff[4];
#pragma unroll
    for (int f = 0; f < 4; ++f) {
        int col = f * 16 + l15;
        bOff[f] = col * BK + ((l4 ^ ((col >> 1) & 3)) << 3);
    }

    // prologue: A(0) frags -> bank0; B(0) convert+write; x(1) prefetch
    U16x8 ah[2][4], al[2][4];
#pragma unroll
    for (int f = 0; f < 4; ++f) {
        ah[0][f].u4 = *(const uint4*)(aHiP + f * 512);
        al[0][f].u4 = *(const uint4*)(aLoP + f * 512);
    }
    float4 p0 = *(const float4*)(xsrc);
    float4 p1 = *(const float4*)(xsrc + 4);
    writeB(0, p0, p1);
    p0 = *(const float4*)(xsrc + BK);
    p1 = *(const float4*)(xsrc + BK + 4);
    __syncthreads();

    f32x4 acc[4][4];
#pragma unroll
    for (int i = 0; i < 4; ++i)
#pragma unroll
        for (int q = 0; q < 4; ++q) acc[i][q] = (f32x4){0.f, 0.f, 0.f, 0.f};

#pragma unroll 2
    for (int kt = 0; kt < NT; ++kt) {
        const int  cur = kt & 1, nxt = cur ^ 1;   // literal under unroll 2
        const bool pf1 = (kt + 1 < NT);
        const bool pf2 = (kt + 2 < NT);

        // B fragments for this K-step (8 ds_read_b128)
        U16x8 bh[4], bl[4];
#pragma unroll
        for (int f = 0; f < 4; ++f) {
            bh[f].u4 = *(const uint4*)&sBhi[cur][bOff[f]];
            bl[f].u4 = *(const uint4*)&sBlo[cur][bOff[f]];
        }

        // A(kt+1) frags -> bank nxt (8 coalesced global loads, L2-hot;
        // in flight across the whole MFMA block and the barrier)
        if (pf1) {
            const ushort* ph = aHiP + (size_t)(kt + 1) * 8192;
            const ushort* pl = aLoP + (size_t)(kt + 1) * 8192;
#pragma unroll
            for (int f = 0; f < 4; ++f) {
                ah[nxt][f].u4 = *(const uint4*)(ph + f * 512);
                al[nxt][f].u4 = *(const uint4*)(pl + f * 512);
            }
        }
        SCHB();   // pin prefetch issue before the MFMA block

        // 48 MFMA (A bank cur register-resident; lgkm for b auto-inserted)
        __builtin_amdgcn_s_setprio(1);
#pragma unroll
        for (int fj = 0; fj < 4; ++fj) {
#pragma unroll
            for (int fi = 0; fi < 4; ++fi) MFMA(acc[fi][fj], ah[cur][fi], bh[fj]);  // hh
#pragma unroll
            for (int fi = 0; fi < 4; ++fi) MFMA(acc[fi][fj], ah[cur][fi], bl[fj]);  // hl
#pragma unroll
            for (int fi = 0; fi < 4; ++fi) MFMA(acc[fi][fj], al[cur][fi], bh[fj]);  // lh
        }
        __builtin_amdgcn_s_setprio(0);

        // convert+write B(kt+1) (auto-vmcnt proves x(kt+1) regs, leaving the
        // A(kt+1) loads in flight), then load x(kt+2)
        if (pf1) writeB(nxt, p0, p1);
        if (pf2) {
            const float* p = xsrc + (kt + 2) * BK;
            p0 = *(const float4*)p;
            p1 = *(const float4*)(p + 4);
        }
        LGKM0();                    // own b-frag reads + B ds_writes complete
        BAR();                      // sB[nxt] visible block-wide
    }

    // x_sq: 4 threads per column
    {
        float v = xs_acc;
        v += __shfl_xor(v, 1);
        v += __shfl_xor(v, 2);
        if (bq == 0) sXsq[bcol] = v;
    }
    __syncthreads();

    // epilogue: distances, argmin, loss
    float xs[4];
    f32x4 cs[4];
#pragma unroll
    for (int f = 0; f < 4; ++f) {
        xs[f] = sXsq[f * 16 + l15];
        cs[f] = *(const f32x4*)&sCsq[w * 64 + f * 16 + l4 * 4];
    }

    float lsum = 0.f;
    float bestv[4];
    int   bestr[4];
#pragma unroll
    for (int f = 0; f < 4; ++f) { bestv[f] = 3.4e38f; bestr[f] = 0; }

#pragma unroll
    for (int fi = 0; fi < 4; ++fi) {
        const int rowB = w * 64 + fi * 16 + l4 * 4;
#pragma unroll
        for (int fj = 0; fj < 4; ++fj) {
            const int col = blk * BN + fj * 16 + l15;
            float* outp = out_dist + (size_t)rowB * N_PTS + col;
#pragma unroll
            for (int j = 0; j < 4; ++j) {
                float d = cs[fi][j] + xs[fj] - 2.0f * acc[fi][fj][j];
                outp[(size_t)j * N_PTS] = d;
                lsum += d;
                int r = rowB + j;
                if (d < bestv[fj]) { bestv[fj] = d; bestr[fj] = r; }
            }
        }
    }

    // wave argmin over the wave's 64 rows (lanes l, l^16, l^32 share a column)
#pragma unroll
    for (int fj = 0; fj < 4; ++fj) {
#pragma unroll
        for (int m = 16; m <= 32; m <<= 1) {
            float ov = __shfl_xor(bestv[fj], m);
            int   orr = __shfl_xor(bestr[fj], m);
            if (ov < bestv[fj] || (ov == bestv[fj] && orr < bestr[fj])) {
                bestv[fj] = ov; bestr[fj] = orr;
            }
        }
        if (lane < 16) {
            sRedV[w * BN + fj * 16 + lane] = bestv[fj];
            sRedI[w * BN + fj * 16 + lane] = bestr[fj];
        }
    }

#pragma unroll
    for (int off = 1; off < 64; off <<= 1) lsum += __shfl_xor(lsum, off);
    if (lane == 0) sWsum[w] = lsum;
    __syncthreads();

    if (tid < BN) {
        float bv = sRedV[tid];
        int   br = sRedI[tid];
#pragma unroll
        for (int q = 1; q < 4; ++q) {
            float v = sRedV[q * BN + tid];
            int   r = sRedI[q * BN + tid];
            if (v < bv || (v == bv && r < br)) { bv = v; br = r; }
        }
        out_assign[blk * BN + tid] = (float)br;
    }
    if (tid == 0) {
        float t = 0.f;
#pragma unroll
        for (int q = 0; q < 4; ++q) t += sWsum[q];
        partials[blk] = t;
    }
}

// ---------------------------------------------------------------------------
// Kernel 2: deterministic loss reduction over 1024 block partials.
// ---------------------------------------------------------------------------
__global__ __launch_bounds__(1024) void km_fin(const float* __restrict__ partials,
                                               float* __restrict__ out_loss) {
    __shared__ float ws[16];
    const int t = threadIdx.x;
    float v = partials[t];
#pragma unroll
    for (int off = 1; off < 64; off <<= 1) v += __shfl_xor(v, off);
    if ((t & 63) == 0) ws[t >> 6] = v;
    __syncthreads();
    if (t == 0) {
        float s = 0.f;
#pragma unroll
        for (int i = 0; i < 16; ++i) s += ws[i];
        out_loss[0] = s / 16777216.0f;   // mean over K*N
    }
}

extern "C" void kernel_launch(void* const* d_in, const int* in_sizes, int n_in,
                              void* d_out, int out_size, void* d_ws, size_t ws_size,
                              hipStream_t stream) {
    const float* x    = (const float*)d_in[0];
    const float* cent = (const float*)d_in[1];

    float* out        = (float*)d_out;
    float* out_dist   = out;                                  // [256][65536]
    float* out_assign = out + (size_t)K_CL * N_PTS;           // [65536] as float
    float* out_loss   = out_assign + N_PTS;                   // [1]

    char*   ws       = (char*)d_ws;
    float*  csq      = (float*)ws;                            // 256 f32
    float*  partials = (float*)(ws + 1024);                   // 1024 f32
    ushort* Ahi      = (ushort*)(ws + 8192);                  // 512 KB
    ushort* Alo      = (ushort*)(ws + 8192 + 524288);         // 512 KB

    km_prep<<<dim3(K_CL), dim3(128), 0, stream>>>(cent, Ahi, Alo, csq);
    km_main<<<dim3(N_PTS / BN), dim3(THREADS), 0, stream>>>(
        x, Ahi, Alo, csq, out_dist, out_assign, partials);
    km_fin<<<dim3(1), dim3(1024), 0, stream>>>(partials, out_loss);
}

// Round 11
// 122.304 us; speedup vs baseline: 6.7023x; 1.1280x over previous
//
#include <hip/hip_runtime.h>
#include <cstdint>

#define N_PTS 65536
#define DIM   1024
#define K_CL  256
#define BN    128
#define BK    32          // kt32 granule (image layout + numerics granule)
#define NKT   16          // K-loop steps of 64 (two kt32 each)
#define THREADS 512

typedef __bf16 bf16_t;
typedef bf16_t bf16x8 __attribute__((ext_vector_type(8)));
typedef float  f32x4  __attribute__((ext_vector_type(4)));

union U16x8 { uint4 u4; bf16x8 bf; ushort us[8]; };

__device__ __forceinline__ ushort f2bf_rne(float f) {
    uint32_t u = __float_as_uint(f);
    uint32_t r = (u + 0x7FFFu + ((u >> 16) & 1u)) >> 16;
    return (ushort)r;
}
__device__ __forceinline__ float bf2f(ushort b) {
    return __uint_as_float(((uint32_t)b) << 16);
}

__device__ __forceinline__ void gll16(const void* g, void* l) {
    __builtin_amdgcn_global_load_lds(
        (const __attribute__((address_space(1))) void*)g,
        (__attribute__((address_space(3))) void*)l, 16, 0, 0);
}

#define BAR()   __builtin_amdgcn_s_barrier()
#define SCHB()  __builtin_amdgcn_sched_barrier(0)
#define LGKM0() do { asm volatile("s_waitcnt lgkmcnt(0)" ::: "memory"); \
                     __builtin_amdgcn_sched_barrier(0); } while (0)
#define VMCNT(N) do { asm volatile("s_waitcnt vmcnt(" #N ")" ::: "memory"); \
                      __builtin_amdgcn_sched_barrier(0); } while (0)
#define MFMA(ACC, A, B) (ACC) = __builtin_amdgcn_mfma_f32_16x16x32_bf16((A).bf, (B).bf, (ACC), 0, 0, 0)

// ---------------------------------------------------------------------------
// Kernel 0: centroids fp32 -> pre-swizzled bf16 hi/lo tile images + c_sq.
// (identical to r6; layout verified)  [NT32 tiles][256 rows][4 grp][8 bf16],
// grp slot gp holds d-group (gp ^ s), s = (row>>1)&3.
// ---------------------------------------------------------------------------
__global__ __launch_bounds__(128) void km_prep(const float* __restrict__ cent,
                                               ushort* __restrict__ Ahi,
                                               ushort* __restrict__ Alo,
                                               float* __restrict__ csq) {
    const int r  = blockIdx.x;
    const int j  = threadIdx.x;
    const int kt = j >> 2;
    const int gp = j & 3;
    const int s  = (r >> 1) & 3;
    const int d0 = kt * BK + ((gp ^ s) << 3);

    const float* src = cent + r * DIM + d0;
    float4 a = *(const float4*)src;
    float4 b = *(const float4*)(src + 4);
    float v[8] = {a.x, a.y, a.z, a.w, b.x, b.y, b.z, b.w};

    U16x8 hi, lo;
    float ss = 0.f;
#pragma unroll
    for (int i = 0; i < 8; ++i) {
        float f = v[i];
        ss += f * f;
        ushort h = f2bf_rne(f);
        hi.us[i] = h;
        lo.us[i] = f2bf_rne(f - bf2f(h));
    }
    *(uint4*)(Ahi + kt * (K_CL * BK) + r * BK + gp * 8) = hi.u4;
    *(uint4*)(Alo + kt * (K_CL * BK) + r * BK + gp * 8) = lo.u4;

#pragma unroll
    for (int off = 1; off < 64; off <<= 1) ss += __shfl_xor(ss, off);
    __shared__ float ws2[2];
    if ((j & 63) == 0) ws2[j >> 6] = ss;
    __syncthreads();
    if (j == 0) csq[r] = ws2[0] + ws2[1];
}

// ---------------------------------------------------------------------------
// Kernel 1: fused distances + argmin + loss partial.
// 512 thr (8 waves), tile 256 (all K) x 128 cols; wave (wr,wc) = 64 x 64.
// K-step = 64 (two kt32 sub-tiles) -> 2 barriers per 64-K = HALF of r6's
// sync frequency; 96 MFMA per wave per barrier-pair.
// Staging split: only tid<256 (r6's exact thread->element map!) convert x
// and prefetch -> each SIMD pairs a stager wave with a pure-MFMA wave, and
// xs_acc / B-conversion / per-acc MFMA sequences are BIT-IDENTICAL to r6
// (distances bit-exact; absmax must stay 16.0).
// A: single-buffered LDS (frags drained to regs in P1 before the freeing
// barrier); B: double-buffered.  Counted vmcnt: stagers keep 8 x-prefetch
// loads in flight across the barrier; never drain to 0 mid-loop.
// ---------------------------------------------------------------------------
__global__ __launch_bounds__(THREADS, 2) void km_main(
    const float* __restrict__ x,
    const ushort* __restrict__ Ahi, const ushort* __restrict__ Alo,
    const float* __restrict__ csq,
    float* __restrict__ out_dist, float* __restrict__ out_assign,
    float* __restrict__ partials) {

    __shared__ __align__(16) ushort sAhi[2][K_CL * BK];      // [ks][8192] 32 KB
    __shared__ __align__(16) ushort sAlo[2][K_CL * BK];      // 32 KB
    __shared__ __align__(16) ushort sBhi[2][2][BN * BK];     // [buf][ks] 32 KB
    __shared__ __align__(16) ushort sBlo[2][2][BN * BK];     // 32 KB
    __shared__ __align__(16) float  sCsq[K_CL];
    __shared__ __align__(16) float  sXsq[BN];
    __shared__ float sRedV[4 * BN];
    __shared__ int   sRedI[4 * BN];
    __shared__ float sWsum[8];

    const int tid  = threadIdx.x;
    const int blk  = blockIdx.x;
    const int lane = tid & 63;
    const int w    = tid >> 6;
    const int wr   = w >> 1;      // 0..3 row group (64 rows)
    const int wc   = w & 1;       // 0..1 col group (64 cols)
    const int l15  = lane & 15;
    const int l4   = lane >> 4;   // 0..3
    const bool stager = (tid < 256);

    if (tid < K_CL) sCsq[tid] = csq[tid];

    // B staging (tid<256 only): EXACT r6 map — 2 threads/col, 16-elem chunks.
    const int bcol  = tid >> 1;                 // 0..127 (stagers)
    const int bhalf = tid & 1;
    const int bs    = (bcol >> 1) & 3;
    const int bOff0 = bcol * BK + ((((bhalf << 1) | 0) ^ bs) << 3);
    const int bOff1 = bcol * BK + ((((bhalf << 1) | 1) ^ bs) << 3);
    const float* xsrc = x + (size_t)(blk * BN + (bcol & 127)) * DIM + bhalf * 16;

    float xs_acc = 0.f;

    // stage one 64-K A super-tile (two kt32 images) -> sA[ks][..], 8 glls
    auto stageA = [&](int kt64) {
        const char* ph = (const char*)Ahi + (size_t)kt64 * 32768 + tid * 16;
        const char* pl = (const char*)Alo + (size_t)kt64 * 32768 + tid * 16;
        char* dh = (char*)&sAhi[0][0] + tid * 16;
        char* dl = (char*)&sAlo[0][0] + tid * 16;
        gll16(ph,         dh);            // ks0 half A
        gll16(ph +  8192, dh +  8192);    // ks0 half B
        gll16(ph + 16384, dh + 16384);    // ks1 half A
        gll16(ph + 24576, dh + 24576);    // ks1 half B
        gll16(pl,         dl);
        gll16(pl +  8192, dl +  8192);
        gll16(pl + 16384, dl + 16384);
        gll16(pl + 24576, dl + 24576);
    };
    // convert+write one kt32 chunk (16 elems) — EXACT r6 writeB body
    auto writeB = [&](int buf, int ks, float4 v0, float4 v1, float4 v2, float4 v3) {
        float f[16] = {v0.x, v0.y, v0.z, v0.w, v1.x, v1.y, v1.z, v1.w,
                       v2.x, v2.y, v2.z, v2.w, v3.x, v3.y, v3.z, v3.w};
        U16x8 h0, h1, l0, l1;
#pragma unroll
        for (int i = 0; i < 8; ++i) {
            float a = f[i];
            xs_acc = fmaf(a, a, xs_acc);
            bf16_t hb = (bf16_t)a;
            h0.bf[i] = hb;
            l0.bf[i] = (bf16_t)(a - (float)hb);
            float b = f[i + 8];
            xs_acc = fmaf(b, b, xs_acc);
            bf16_t hc = (bf16_t)b;
            h1.bf[i] = hc;
            l1.bf[i] = (bf16_t)(b - (float)hc);
        }
        *(uint4*)&sBhi[buf][ks][bOff0] = h0.u4;
        *(uint4*)&sBhi[buf][ks][bOff1] = h1.u4;
        *(uint4*)&sBlo[buf][ks][bOff0] = l0.u4;
        *(uint4*)&sBlo[buf][ks][bOff1] = l1.u4;
    };

    // fragment LDS offsets (ushort units), swizzle folded in
    int aOff[4], bOff[4];
#pragma unroll
    for (int f = 0; f < 4; ++f) {
        int row  = wr * 64 + f * 16 + l15;
        aOff[f]  = row * BK + ((l4 ^ ((row >> 1) & 3)) << 3);
        int col  = wc * 64 + f * 16 + l15;
        bOff[f]  = col * BK + ((l4 ^ ((col >> 1) & 3)) << 3);
    }

    // prologue: stage A(0); convert B(0) both chunks; prefetch x(1)
    float4 pA0, pA1, pA2, pA3, pB0, pB1, pB2, pB3;
    stageA(0);
    if (stager) {
        pA0 = *(const float4*)(xsrc);
        pA1 = *(const float4*)(xsrc + 4);
        pA2 = *(const float4*)(xsrc + 8);
        pA3 = *(const float4*)(xsrc + 12);
        pB0 = *(const float4*)(xsrc + 32);
        pB1 = *(const float4*)(xsrc + 36);
        pB2 = *(const float4*)(xsrc + 40);
        pB3 = *(const float4*)(xsrc + 44);
        writeB(0, 0, pA0, pA1, pA2, pA3);
        writeB(0, 1, pB0, pB1, pB2, pB3);
        const float* p = xsrc + 64;
        pA0 = *(const float4*)p;       pA1 = *(const float4*)(p + 4);
        pA2 = *(const float4*)(p + 8); pA3 = *(const float4*)(p + 12);
        pB0 = *(const float4*)(p + 32); pB1 = *(const float4*)(p + 36);
        pB2 = *(const float4*)(p + 40); pB3 = *(const float4*)(p + 44);
    }
    __syncthreads();

    f32x4 acc[4][4];
#pragma unroll
    for (int i = 0; i < 4; ++i)
#pragma unroll
        for (int q = 0; q < 4; ++q) acc[i][q] = (f32x4){0.f, 0.f, 0.f, 0.f};

    int buf = 0;
    for (int kt = 0; kt < NKT; ++kt) {
        const bool pf1 = (kt + 1 < NKT);
        const bool pf2 = (kt + 2 < NKT);

        // ---- P1: drain A-frags (both k-slices) into regs, then free sA ----
        U16x8 ah[2][4], al[2][4];
#pragma unroll
        for (int ks = 0; ks < 2; ++ks)
#pragma unroll
            for (int f = 0; f < 4; ++f) {
                ah[ks][f].u4 = *(const uint4*)&sAhi[ks][aOff[f]];
                al[ks][f].u4 = *(const uint4*)&sAlo[ks][aOff[f]];
            }
        LGKM0();
        BAR();

        // ---- P2: stage A(kt+1) | convert+write B(kt+1) | prefetch x(kt+2)
        //          | 96 MFMA | counted vmcnt | barrier ----
        if (pf1) stageA(kt + 1);                   // 8 glls (oldest vmem)
        SCHB();
        if (stager && pf1) {
            writeB(buf ^ 1, 0, pA0, pA1, pA2, pA3);   // compiler vmcnt proves p
            writeB(buf ^ 1, 1, pB0, pB1, pB2, pB3);   // (glls stay in flight)
        }
        if (stager && pf2) {
            const float* p = xsrc + (size_t)(kt + 2) * 64;
            pA0 = *(const float4*)p;        pA1 = *(const float4*)(p + 4);
            pA2 = *(const float4*)(p + 8);  pA3 = *(const float4*)(p + 12);
            pB0 = *(const float4*)(p + 32); pB1 = *(const float4*)(p + 36);
            pB2 = *(const float4*)(p + 40); pB3 = *(const float4*)(p + 44);
        }
        SCHB();

        __builtin_amdgcn_s_setprio(1);
#pragma unroll
        for (int ks = 0; ks < 2; ++ks) {
#pragma unroll
            for (int fj = 0; fj < 4; ++fj) {
                U16x8 bh, bl;
                bh.u4 = *(const uint4*)&sBhi[buf][ks][bOff[fj]];
                bl.u4 = *(const uint4*)&sBlo[buf][ks][bOff[fj]];
#pragma unroll
                for (int fi = 0; fi < 4; ++fi) MFMA(acc[fi][fj], ah[ks][fi], bh);  // hh
#pragma unroll
                for (int fi = 0; fi < 4; ++fi) MFMA(acc[fi][fj], ah[ks][fi], bl);  // hl
#pragma unroll
                for (int fi = 0; fi < 4; ++fi) MFMA(acc[fi][fj], al[ks][fi], bh);  // lh
            }
        }
        __builtin_amdgcn_s_setprio(0);

        if (pf1) {
            if (stager && pf2) { VMCNT(8); }   // glls done; 8 x-loads in flight
            else              { VMCNT(0); }    // tail / non-stagers: drain glls
        }
        LGKM0();                   // own B ds_reads + (stagers') ds_writes
        BAR();                     // sA(kt+1) + sB[buf^1] ready block-wide
        buf ^= 1;
    }

    // x_sq: EXACT r6 reduction (stagers only)
    if (stager) {
        float v = xs_acc;
        v += __shfl_xor(v, 1);
        if (bhalf == 0) sXsq[bcol] = v;
    }
    __syncthreads();

    // epilogue: distances, argmin, loss
    const int colBase = wc * 64;
    float xs[4];
    f32x4 cs[4];
#pragma unroll
    for (int f = 0; f < 4; ++f) {
        xs[f] = sXsq[colBase + f * 16 + l15];
        cs[f] = *(const f32x4*)&sCsq[wr * 64 + f * 16 + l4 * 4];
    }

    float lsum = 0.f;
    float bestv[4];
    int   bestr[4];
#pragma unroll
    for (int f = 0; f < 4; ++f) { bestv[f] = 3.4e38f; bestr[f] = 0; }

#pragma unroll
    for (int fi = 0; fi < 4; ++fi) {
        const int rowB = wr * 64 + fi * 16 + l4 * 4;
#pragma unroll
        for (int fj = 0; fj < 4; ++fj) {
            const int col = blk * BN + colBase + fj * 16 + l15;
            float* outp = out_dist + (size_t)rowB * N_PTS + col;
#pragma unroll
            for (int j = 0; j < 4; ++j) {
                float d = cs[fi][j] + xs[fj] - 2.0f * acc[fi][fj][j];
                outp[(size_t)j * N_PTS] = d;
                lsum += d;
                int r = rowB + j;
                if (d < bestv[fj]) { bestv[fj] = d; bestr[fj] = r; }
            }
        }
    }

    // wave argmin over the wave's 64 rows (lanes l, l^16, l^32 share a column)
#pragma unroll
    for (int fj = 0; fj < 4; ++fj) {
#pragma unroll
        for (int m = 16; m <= 32; m <<= 1) {
            float ov = __shfl_xor(bestv[fj], m);
            int   orr = __shfl_xor(bestr[fj], m);
            if (ov < bestv[fj] || (ov == bestv[fj] && orr < bestr[fj])) {
                bestv[fj] = ov; bestr[fj] = orr;
            }
        }
        if (lane < 16) {
            sRedV[wr * BN + colBase + fj * 16 + lane] = bestv[fj];
            sRedI[wr * BN + colBase + fj * 16 + lane] = bestr[fj];
        }
    }

#pragma unroll
    for (int off = 1; off < 64; off <<= 1) lsum += __shfl_xor(lsum, off);
    if (lane == 0) sWsum[w] = lsum;
    __syncthreads();

    if (tid < BN) {
        float bv = sRedV[tid];
        int   br = sRedI[tid];
#pragma unroll
        for (int q = 1; q < 4; ++q) {
            float v = sRedV[q * BN + tid];
            int   r = sRedI[q * BN + tid];
            if (v < bv || (v == bv && r < br)) { bv = v; br = r; }
        }
        out_assign[blk * BN + tid] = (float)br;
    }
    if (tid == 0) {
        float t = 0.f;
#pragma unroll
        for (int q = 0; q < 8; ++q) t += sWsum[q];
        partials[blk] = t;
    }
}

// ---------------------------------------------------------------------------
// Kernel 2: deterministic loss reduction over 512 block partials.
// ---------------------------------------------------------------------------
__global__ __launch_bounds__(512) void km_fin(const float* __restrict__ partials,
                                              float* __restrict__ out_loss) {
    __shared__ float ws[8];
    const int t = threadIdx.x;
    float v = partials[t];
#pragma unroll
    for (int off = 1; off < 64; off <<= 1) v += __shfl_xor(v, off);
    if ((t & 63) == 0) ws[t >> 6] = v;
    __syncthreads();
    if (t == 0) {
        float s = 0.f;
#pragma unroll
        for (int i = 0; i < 8; ++i) s += ws[i];
        out_loss[0] = s / 16777216.0f;   // mean over K*N
    }
}

extern "C" void kernel_launch(void* const* d_in, const int* in_sizes, int n_in,
                              void* d_out, int out_size, void* d_ws, size_t ws_size,
                              hipStream_t stream) {
    const float* x    = (const float*)d_in[0];
    const float* cent = (const float*)d_in[1];

    float* out        = (float*)d_out;
    float* out_dist   = out;                                  // [256][65536]
    float* out_assign = out + (size_t)K_CL * N_PTS;           // [65536] as float
    float* out_loss   = out_assign + N_PTS;                   // [1]

    char*   ws       = (char*)d_ws;
    float*  csq      = (float*)ws;                            // 256 f32
    float*  partials = (float*)(ws + 1024);                   // 512 f32
    ushort* Ahi      = (ushort*)(ws + 4096);                  // 512 KB
    ushort* Alo      = (ushort*)(ws + 4096 + 524288);         // 512 KB

    km_prep<<<dim3(K_CL), dim3(128), 0, stream>>>(cent, Ahi, Alo, csq);
    km_main<<<dim3(N_PTS / BN), dim3(THREADS), 0, stream>>>(
        x, Ahi, Alo, csq, out_dist, out_assign, partials);
    km_fin<<<dim3(1), dim3(512), 0, stream>>>(partials, out_loss);
}